// Round 2
// baseline (8506.169 us; speedup 1.0000x reference)
//
#include <hip/hip_runtime.h>
#include <stdint.h>

// PolicyNetRSNNPB: 2-layer LIF RSNN + leaky readout, 128 steps, 1 block/sample.
// R2 changes vs R1 (7867us, FETCH 29.5GB, latency-serial gather):
//  - spike index LIST built in LDS (deterministic ascending order) ->
//    uniform counted gather loop unrolled x8 => 32 loads in flight/thread.
//  - XW read/write non-temporal + even-step row cached in LDS => no LLC
//    pollution; Vr/Wf (32MB) stay LLC-resident.
//  - readout gather parallelized over 512 threads (8-way split + reduce).

#define NSTEPS 128
#define NB 512
#define HDIM 2048
#define INDIM 128
#define AOUT 64           // 2*A
#define THREADS 512
#define CPT 4             // HDIM / THREADS
#define NWORDS 32         // HDIM / 64
#define UNR 8

__device__ __forceinline__ float dcy_m() { return 0.8187307530779818f; }
__device__ __forceinline__ float dcy_s() { return 0.6065306597126334f; }
__device__ __forceinline__ float scl_m() { return 0.18126924692201818f; }

// ---------------- XW precompute: XW[t*NB+n][h] = bi[h] + x(t,n,:) @ Wi ----------------
__global__ __launch_bounds__(256) void xw_kernel(
    const float* __restrict__ state, const float* __restrict__ target,
    const float* __restrict__ Wi, const float* __restrict__ bi,
    float* __restrict__ XW) {
  __shared__ float xl[16][INDIM];
  const int tid = threadIdx.x;
  const int col = blockIdx.x * 256 + tid;
  const int r0 = blockIdx.y * 16;

  for (int idx = tid; idx < 16 * INDIM; idx += 256) {
    int r = idx >> 7, k = idx & 127;
    int g = r0 + r;              // g = t*NB + n
    int t = g >> 9, n = g & 511;
    float v = (k < 64) ? state[((size_t)(t * NB + n)) * 64 + k]
                       : target[((size_t)(t * NB + n)) * 64 + (k - 64)];
    xl[r][k] = v;
  }
  __syncthreads();

  float acc[16];
  float b = bi[col];
#pragma unroll
  for (int r = 0; r < 16; ++r) acc[r] = b;
  for (int k = 0; k < INDIM; ++k) {
    float w = Wi[(size_t)k * HDIM + col];
#pragma unroll
    for (int r = 0; r < 16; ++r) acc[r] = fmaf(xl[r][k], w, acc[r]);
  }
#pragma unroll
  for (int r = 0; r < 16; ++r)
    __builtin_nontemporal_store(acc[r], &XW[(size_t)(r0 + r) * HDIM + col]);
}

// gather: acc[i] += sum over rows in list of W[row][i*THREADS+tid],
// ascending list order (bit-exact vs reference mask-walk order).
__device__ __forceinline__ void gather_acc(const float* __restrict__ W,
                                           const uint16_t* list, int cnt,
                                           int tid, float* acc) {
  int j = 0;
  for (; j + UNR <= cnt; j += UNR) {
    const float* rows[UNR];
#pragma unroll
    for (int u = 0; u < UNR; ++u)
      rows[u] = W + (size_t)list[j + u] * HDIM;
    float v[UNR][CPT];
#pragma unroll
    for (int u = 0; u < UNR; ++u)
#pragma unroll
      for (int i = 0; i < CPT; ++i)
        v[u][i] = rows[u][i * THREADS + tid];
#pragma unroll
    for (int u = 0; u < UNR; ++u)
#pragma unroll
      for (int i = 0; i < CPT; ++i)
        acc[i] += v[u][i];
  }
  for (; j < cnt; ++j) {
    const float* row = W + (size_t)list[j] * HDIM;
#pragma unroll
    for (int i = 0; i < CPT; ++i)
      acc[i] += row[i * THREADS + tid];
  }
}

// wave 0 builds ascending index list from 32 mask words (prefix scan).
__device__ __forceinline__ void build_list(const unsigned long long* m,
                                           uint16_t* list, int* cnt, int tid) {
  if (tid < 64) {
    unsigned long long w = (tid < NWORDS) ? m[tid] : 0ULL;
    int pc = __popcll(w);
    int pre = pc;
#pragma unroll
    for (int off = 1; off < 64; off <<= 1) {
      int v = __shfl_up(pre, off);
      if (tid >= off) pre += v;
    }
    int excl = pre - pc;
    if (tid == 63) *cnt = pre;
    const int kbase = tid << 6;
    while (w) {
      int b = __builtin_ctzll(w);
      w &= w - 1;
      list[excl++] = (uint16_t)(kbase + b);
    }
  }
}

// ---------------- main persistent per-sample kernel ----------------
__global__ __launch_bounds__(THREADS, 4) void rsnn_kernel(
    const float* __restrict__ state, const float* __restrict__ target,
    const float* __restrict__ Wi, const float* __restrict__ bi,
    const float* __restrict__ Vr, const float* __restrict__ Wf,
    const float* __restrict__ bf, const float* __restrict__ Wo,
    const float* __restrict__ bo, const float* __restrict__ XW,
    float* __restrict__ out, int use_xw) {
  __shared__ float syn1[HDIM], mem1[HDIM], syn2[HDIM], mem2[HDIM];
  __shared__ unsigned long long m1[NWORDS], m2[NWORDS];
  __shared__ uint16_t list1[HDIM], list2[HDIM];
  __shared__ int cnt1, cnt2;
  __shared__ float synr[AOUT], memr[AOUT], roprev[AOUT];
  __shared__ float ro_part[8][AOUT];
  __shared__ float xbuf[INDIM];
  __shared__ float xw_lds[HDIM];

  const int n = blockIdx.x;
  const int tid = threadIdx.x;
  const int wv = tid >> 6;
  const int lane = tid & 63;

  for (int h = tid; h < HDIM; h += THREADS) {
    syn1[h] = 0.0f; mem1[h] = 0.0f; syn2[h] = 0.0f; mem2[h] = 0.0f;
  }
  if (tid < NWORDS) { m1[tid] = 0ULL; m2[tid] = 0ULL; }
  if (tid == 0) { cnt1 = 0; cnt2 = 0; }
  if (tid < AOUT) { synr[tid] = 0.0f; memr[tid] = 0.0f; roprev[tid] = 0.0f; }
  __syncthreads();

  float bfr[CPT];
#pragma unroll
  for (int i = 0; i < CPT; ++i) bfr[i] = bf[i * THREADS + tid];
  const float bor = (tid < AOUT) ? bo[tid] : 0.0f;

  const float dm = dcy_m(), ds = dcy_s(), sm = scl_m();
  const int g = tid >> 6;       // readout row-group
  const int c = tid & 63;       // readout column

  for (int step = 0; step < NSTEPS; ++step) {
    const int t = step >> 1;

    // ---- xw for this step -> registers (and xw_lds on even steps) ----
    float acc[CPT];
    if ((step & 1) == 0) {
      if (use_xw) {
        const float* xwrow = XW + ((size_t)(t * NB + n)) * HDIM;
#pragma unroll
        for (int i = 0; i < CPT; ++i) {
          acc[i] = __builtin_nontemporal_load(&xwrow[i * THREADS + tid]);
          xw_lds[i * THREADS + tid] = acc[i];
        }
      } else {
        if (tid < INDIM) {
          xbuf[tid] = (tid < 64) ? state[((size_t)(t * NB + n)) * 64 + tid]
                                 : target[((size_t)(t * NB + n)) * 64 + (tid - 64)];
        }
        __syncthreads();
#pragma unroll
        for (int i = 0; i < CPT; ++i) {
          int h = i * THREADS + tid;
          float a = bi[h];
          for (int k = 0; k < INDIM; ++k) a = fmaf(xbuf[k], Wi[(size_t)k * HDIM + h], a);
          xw_lds[h] = a;
          acc[i] = a;
        }
        __syncthreads();
      }
    } else {
#pragma unroll
      for (int i = 0; i < CPT; ++i) acc[i] = xw_lds[i * THREADS + tid];
    }

    // ================= layer 1: I1 = xw + s1_old @ Vr =================
    gather_acc(Vr, list1, cnt1, tid, acc);

    float nm1[CPT];
#pragma unroll
    for (int i = 0; i < CPT; ++i) {
      int h = i * THREADS + tid;
      float so = (float)((m1[i * 8 + wv] >> lane) & 1ULL);
      float nmem = (dm * mem1[h] + sm * syn1[h]) * (1.0f - so);
      float nsyn = ds * syn1[h] + acc[i];
      mem1[h] = nmem; syn1[h] = nsyn;
      nm1[i] = nmem;
    }
    __syncthreads();                      // old m1 / old list1 fully consumed
#pragma unroll
    for (int i = 0; i < CPT; ++i) {
      unsigned long long bm = __ballot((nm1[i] - 1.0f) > 0.0f);
      if (lane == 0) m1[i * 8 + wv] = bm;
    }
    __syncthreads();                      // new m1 visible
    build_list(m1, list1, &cnt1, tid);
    __syncthreads();                      // list1 / cnt1 ready

    // ================= layer 2: I2 = bf + ns1 @ Wf =================
    float acc2[CPT];
#pragma unroll
    for (int i = 0; i < CPT; ++i) acc2[i] = bfr[i];
    gather_acc(Wf, list1, cnt1, tid, acc2);

    float nm2[CPT];
#pragma unroll
    for (int i = 0; i < CPT; ++i) {
      int h = i * THREADS + tid;
      float so = (float)((m2[i * 8 + wv] >> lane) & 1ULL);
      float nmem = (dm * mem2[h] + sm * syn2[h]) * (1.0f - so);
      float nsyn = ds * syn2[h] + acc2[i];
      mem2[h] = nmem; syn2[h] = nsyn;
      nm2[i] = nmem;
    }
    __syncthreads();                      // old m2 consumed
#pragma unroll
    for (int i = 0; i < CPT; ++i) {
      unsigned long long bm = __ballot((nm2[i] - 1.0f) > 0.0f);
      if (lane == 0) m2[i * 8 + wv] = bm;
    }
    __syncthreads();                      // new m2 visible
    build_list(m2, list2, &cnt2, tid);
    __syncthreads();                      // list2 / cnt2 ready

    // ================= readout: Ir = bo + ns2 @ Wo =================
    {
      float pa = 0.0f;
      for (int j = g; j < cnt2; j += 8)
        pa += Wo[(size_t)list2[j] * AOUT + c];
      ro_part[g][c] = pa;
    }
    __syncthreads();                      // partials ready
    if (tid < AOUT) {
      float a = bor;
#pragma unroll
      for (int gg = 0; gg < 8; ++gg) a += ro_part[gg][tid];
      float nmemr = dm * memr[tid] + sm * synr[tid];   // old synr!
      float nsynr = ds * synr[tid] + a;
      memr[tid] = nmemr; synr[tid] = nsynr;
      if (step & 1) {
        float v = 0.5f * (roprev[tid] + nmemr);
        size_t base = ((size_t)t * NB + n) * 32;
        if (tid < 32) out[base + tid] = v;
        else          out[(size_t)(64 * NB * 32) + base + (tid - 32)] = v;
      } else {
        roprev[tid] = nmemr;
      }
    }
    // no extra sync: next write to ro_part is behind multiple barriers
  }
}

extern "C" void kernel_launch(void* const* d_in, const int* in_sizes, int n_in,
                              void* d_out, int out_size, void* d_ws, size_t ws_size,
                              hipStream_t stream) {
  const float* state  = (const float*)d_in[0];
  const float* target = (const float*)d_in[1];
  const float* Wi     = (const float*)d_in[2];
  const float* bi     = (const float*)d_in[3];
  const float* Vr     = (const float*)d_in[4];
  const float* Wf     = (const float*)d_in[5];
  const float* bf     = (const float*)d_in[6];
  const float* Wo     = (const float*)d_in[7];
  const float* bo     = (const float*)d_in[8];
  float* out = (float*)d_out;

  const size_t xw_bytes = (size_t)64 * NB * HDIM * sizeof(float);  // 256 MB
  int use_xw = (ws_size >= xw_bytes) ? 1 : 0;
  float* XW = (float*)d_ws;

  if (use_xw) {
    xw_kernel<<<dim3(8, 2048), 256, 0, stream>>>(state, target, Wi, bi, XW);
  }
  rsnn_kernel<<<NB, THREADS, 0, stream>>>(state, target, Wi, bi, Vr, Wf, bf,
                                          Wo, bo, XW, out, use_xw);
}